// Round 8
// baseline (70.303 us; speedup 1.0000x reference)
//
#include <hip/hip_runtime.h>
#include <math.h>

#define B_    8
#define C_    128
#define L_    8192
#define O_    128
#define POS_  10
#define CHIN  798
#define CH_   266          // 128 direct + 128 gathered + 10 penc
#define CPAD  288          // 9 chunks * 32
#define NCH   9
#define TL2   256
#define G_ELEMS  ((size_t)B_ * L_ * CPAD)   // f16: 37.75 MB
#define WT_ELEMS ((size_t)3 * O_ * CPAD)    // f16: 221 KB

typedef _Float16 half8 __attribute__((ext_vector_type(8)));
typedef short short8 __attribute__((ext_vector_type(8)));
typedef float f32x4  __attribute__((ext_vector_type(4)));

// ---------------------------------------------------------------------------
// Fused mask-dtype detection, single block, writes derived mflag:
//   1 = byte/bool, 0 = int32, 2 = int64
// ---------------------------------------------------------------------------
__global__ void detect_fused(const uint4* __restrict__ m, int* __restrict__ mflag) {
    __shared__ int s[2];
    const int tid = threadIdx.x;                 // 1024 threads
    if (tid < 2) s[tid] = 0;
    __syncthreads();
    unsigned sub = 0, mid = 0;
    #pragma unroll
    for (int k = 0; k < 4; ++k) {
        uint4 w = m[tid + k * 1024];             // 4096 * 16B = 64 KB
        sub |= (w.x | w.y | w.z | w.w) & 0xFFFFFF00u;
        mid |= (w.y | w.w) & 0x000000FFu;
    }
    unsigned long long bs = __ballot(sub != 0);
    unsigned long long bm = __ballot(mid != 0);
    if ((tid & 63) == 0) {
        if (bs) atomicOr(&s[0], 1);
        if (bm) atomicOr(&s[1], 1);
    }
    __syncthreads();
    if (tid == 0) mflag[0] = s[0] ? 1 : (s[1] ? 0 : 2);
}

// ---------------------------------------------------------------------------
// prep: blocks [0,2048): transpose inputs[b,c,l] f32 -> G[b,l,c] f16
//       blocks [2048,2480): Wt[t][o][c] = (f16) W[o][3c+t] (c<266 else 0)
// ---------------------------------------------------------------------------
__global__ __launch_bounds__(256, 4)
void prep_kernel(const float* __restrict__ inputs, const float* __restrict__ W,
                 _Float16* __restrict__ G, _Float16* __restrict__ Wt) {
    __shared__ float tile[64][65];
    const int bid = blockIdx.x;
    const int tid = threadIdx.x;

    if (bid >= 2048) {   // Wt prep: 432 blocks * 256 = 110,592 elems exact
        int idx = (bid - 2048) * 256 + tid;
        int c   = idx % CPAD;
        int rem = idx / CPAD;
        int o   = rem & 127;
        int t   = rem >> 7;
        Wt[idx] = (c < CH_) ? (_Float16)W[o * CHIN + 3 * c + t] : (_Float16)0.f;
        return;
    }

    const int b  = bid & 7;          // b -> XCD affinity
    const int r  = bid >> 3;
    const int c0 = (r & 1) * 64;
    const int l0 = (r >> 1) * 64;
    const int ty = tid >> 6, tx = tid & 63;

    #pragma unroll
    for (int it = 0; it < 16; ++it) {
        int cl = it * 4 + ty;
        tile[cl][tx] = inputs[((size_t)(b * C_ + c0 + cl)) * L_ + l0 + tx];
    }
    __syncthreads();
    const int cp = (tid & 31) * 2;
    const int lr = tid >> 5;          // 0..7
    #pragma unroll
    for (int it = 0; it < 8; ++it) {
        int ll = it * 8 + lr;
        _Float16 pair[2] = {(_Float16)tile[cp][ll], (_Float16)tile[cp + 1][ll]};
        *(unsigned*)&G[((size_t)(b * L_ + l0 + ll)) * CPAD + c0 + cp] = *(unsigned*)pair;
    }
}

// ---------------------------------------------------------------------------
// K1: gather rows + positional encoding into G (f16)
// ---------------------------------------------------------------------------
__global__ __launch_bounds__(256, 4)
void k1_gather_penc(const int* __restrict__ conn, _Float16* __restrict__ G) {
    const int bid = blockIdx.x;
    const int b  = bid & 7;                  // XCD affinity: G[b] slab in XCD L2
    const int l0 = (bid >> 3) * 64;
    const int tid = threadIdx.x;
    const int wv = tid >> 6, lane = tid & 63;

    // gather: 2 rows per wave-iter, 8B per lane
    #pragma unroll
    for (int i = 0; i < 8; ++i) {
        int l  = l0 + wv * 16 + i * 2 + (lane >> 5);
        int cj = conn[b * L_ + l];
        uint2 v = *(const uint2*)&G[((size_t)(b * L_ + cj)) * CPAD + (lane & 31) * 4];
        *(uint2*)&G[((size_t)(b * L_ + l)) * CPAD + 128 + (lane & 31) * 4] = v;
    }

    // penc: thread -> (l, 8-wide c' group)
    {
        int l = l0 + (tid >> 2);
        int s = tid & 3;
        int cj = conn[b * L_ + l];
        float d = (float)(l - cj);
        _Float16 v[8];
        #pragma unroll
        for (int e = 0; e < 8; ++e) {
            int p = s * 8 + e;
            if (p < POS_) {
                float sc = (float)(1 << p);
                v[e] = (_Float16)sinf((sc * d) / 1000.0f);
            } else v[e] = (_Float16)0.f;
        }
        *(short8*)&G[((size_t)(b * L_ + l)) * CPAD + 256 + s * 8] = *(short8*)v;
    }
}

// ---------------------------------------------------------------------------
// K2: f16 MFMA GEMM. grid 256 flat (b = bid&7 -> XCD). 512 thr = 8 waves,
// wave 64o x 64l. A (Wt) streamed from global (L1/L2-resident, no LDS);
// B double-buffered in LDS, ONE barrier per chunk, async-style staging.
// ---------------------------------------------------------------------------
__global__ __launch_bounds__(512, 2)
void k2_gemm(const _Float16* __restrict__ G, const _Float16* __restrict__ Wt,
             const unsigned char* __restrict__ mask,
             const float* __restrict__ bias,
             float* __restrict__ out,
             const int* __restrict__ mflag_p) {
    __shared__ _Float16 Bs[2][260][40];   // 41.6 KB ; rows l0-1 .. l0+256

    const int bid = blockIdx.x;
    const int b   = bid & 7;
    const int l0  = (bid >> 3) * TL2;
    const int tid  = threadIdx.x;
    const int wave = tid >> 6;
    const int lane = tid & 63;
    const int wo = wave & 1;
    const int wl = wave >> 1;
    const int g  = lane >> 4;
    const int ln = lane & 15;

    const _Float16* gb = G + (size_t)b * L_ * CPAD;

    // staging index mapping: q in [0,1032): cb = q&3 (8-f16 block), j = q>>2 (row)
    const int q0 = tid, q1 = tid + 512, q2 = 1024 + tid;   // q2 only for tid<8

#define BLOAD(sreg, q, c0n) { int cb_ = (q) & 3, j_ = (q) >> 2; int l_ = l0 - 1 + j_; \
        sreg = (short8)0; \
        if ((unsigned)l_ < (unsigned)L_) sreg = *(const short8*)&gb[(size_t)l_ * CPAD + (c0n) + cb_ * 8]; }
#define BWRITE(sreg, q, buf) { int cb_ = (q) & 3, j_ = (q) >> 2; \
        *(short8*)&Bs[buf][j_][cb_ * 8] = sreg; }

    f32x4 acc[4][4];
    #pragma unroll
    for (int m = 0; m < 4; ++m)
        #pragma unroll
        for (int n = 0; n < 4; ++n) acc[m][n] = (f32x4)0.f;

    // prologue: stage chunk 0 into buf 0
    {
        short8 s0, s1, s2;
        BLOAD(s0, q0, 0); BLOAD(s1, q1, 0);
        if (tid < 8) { BLOAD(s2, q2, 0); }
        BWRITE(s0, q0, 0); BWRITE(s1, q1, 0);
        if (tid < 8) { BWRITE(s2, q2, 0); }
    }
    __syncthreads();

    int cur = 0;
    for (int ch = 0; ch < NCH; ++ch) {
        const int c0 = ch * 32;
        const bool more = (ch + 1 < NCH);

        // issue next-chunk global loads early (hide HBM/L2 latency under MFMA)
        short8 s0, s1, s2;
        if (more) {
            const int c0n = c0 + 32;
            BLOAD(s0, q0, c0n); BLOAD(s1, q1, c0n);
            if (tid < 8) { BLOAD(s2, q2, c0n); }
        }

        // compute: 3 taps; B frags from LDS, A frags direct from global (L1/L2)
        #pragma unroll
        for (int t = 0; t < 3; ++t) {
            half8 bf[4];
            #pragma unroll
            for (int n = 0; n < 4; ++n)
                bf[n] = *(const half8*)&Bs[cur][wl * 64 + n * 16 + ln + t][8 * g];
            #pragma unroll
            for (int m = 0; m < 4; ++m) {
                const half8 af = *(const half8*)&Wt[((size_t)(t * O_ + wo * 64 + m * 16 + ln)) * CPAD + c0 + 8 * g];
                #pragma unroll
                for (int n = 0; n < 4; ++n)
                    acc[m][n] = __builtin_amdgcn_mfma_f32_16x16x32_f16(af, bf[n], acc[m][n], 0, 0, 0);
            }
        }

        if (more) {
            BWRITE(s0, q0, cur ^ 1); BWRITE(s1, q1, cur ^ 1);
            if (tid < 8) { BWRITE(s2, q2, cur ^ 1); }
            __syncthreads();
            cur ^= 1;
        }
    }

    // epilogue: D col = lane&15 (l), row = g*4+r (o) within frag
    const int mflag = mflag_p[0];
    float mv[4];
    #pragma unroll
    for (int n = 0; n < 4; ++n) {
        int l = l0 + wl * 64 + n * 16 + ln;
        int idx = b * L_ + l;
        if (mflag == 1)      mv[n] = mask[idx] ? 1.f : 0.f;
        else if (mflag == 0) mv[n] = ((const int*)mask)[idx] ? 1.f : 0.f;
        else                 mv[n] = ((const int*)mask)[2 * idx] ? 1.f : 0.f;
    }
    #pragma unroll
    for (int m = 0; m < 4; ++m) {
        #pragma unroll
        for (int r = 0; r < 4; ++r) {
            int o = wo * 64 + m * 16 + g * 4 + r;
            float bo = bias[o];
            #pragma unroll
            for (int n = 0; n < 4; ++n) {
                int l = l0 + wl * 64 + n * 16 + ln;
                out[((size_t)(b * O_ + o)) * L_ + l] = (acc[m][n][r] + bo) * mv[n];
            }
        }
    }
#undef BLOAD
#undef BWRITE
}

// ---------------------------------------------------------------------------
// Fallback (fp32 vector path) if workspace too small
// ---------------------------------------------------------------------------
__global__ __launch_bounds__(256, 2)
void cc_fallback_kernel(const float* __restrict__ inputs,
                        const int* __restrict__ conn,
                        const unsigned char* __restrict__ mask,
                        const float* __restrict__ W,
                        const float* __restrict__ bias,
                        float* __restrict__ out,
                        const int* __restrict__ mflag_p) {
    __shared__ int   conn_s[130];
    __shared__ float feat_s[16][132];
    __shared__ float Ws[48][136];

    const int b   = blockIdx.y;
    const int l0  = blockIdx.x * 128;
    const int tid = threadIdx.x;
    const int ot  = tid >> 4;
    const int lt  = tid & 15;
    const int o0  = ot * 8;
    const int ll  = lt * 8;

    for (int j = tid; j < 130; j += 256) {
        int lg = l0 - 1 + j;
        conn_s[j] = ((unsigned)lg < (unsigned)L_) ? conn[b * L_ + lg] : -1;
    }
    float acc[8][8];
    #pragma unroll
    for (int i = 0; i < 8; ++i)
        #pragma unroll
        for (int j = 0; j < 8; ++j) acc[i][j] = 0.f;

    const int tc = ot, tj = lt;
    for (int chunk = 0; chunk < 17; ++chunk) {
        const int CN  = (chunk < 16) ? 16 : POS_;
        const int cg0 = chunk * 16;
        const int col0 = 3 * cg0;
        __syncthreads();
        {
            const int nw = O_ * CN * 3;
            for (int idx = tid; idx < nw; idx += 256) {
                int o = idx & 127, kk = idx >> 7;
                Ws[kk][o] = W[o * CHIN + col0 + kk];
            }
        }
        if (chunk < 8) {
            const float* src = inputs + ((size_t)b * C_ + (cg0 + tc)) * L_;
            for (int j = tj; j < 130; j += 16) {
                int lg = l0 - 1 + j;
                feat_s[tc][j] = ((unsigned)lg < (unsigned)L_) ? src[lg] : 0.f;
            }
        } else if (chunk < 16) {
            const float* src = inputs + ((size_t)b * C_ + (cg0 - 128 + tc)) * L_;
            for (int j = tj; j < 130; j += 16) {
                int cj = conn_s[j];
                feat_s[tc][j] = (cj >= 0) ? src[cj] : 0.f;
            }
        } else if (tc < POS_) {
            const float sc = (float)(1 << tc);
            for (int j = tj; j < 130; j += 16) {
                int cj = conn_s[j];
                int lg = l0 - 1 + j;
                float v = 0.f;
                if (cj >= 0) v = sinf((sc * (float)(lg - cj)) / 1000.0f);
                feat_s[tc][j] = v;
            }
        }
        __syncthreads();
        for (int c = 0; c < CN; ++c) {
            float f[10];
            float4 fa = *(const float4*)&feat_s[c][ll];
            float4 fb = *(const float4*)&feat_s[c][ll + 4];
            float2 fc2 = *(const float2*)&feat_s[c][ll + 8];
            f[0]=fa.x; f[1]=fa.y; f[2]=fa.z; f[3]=fa.w;
            f[4]=fb.x; f[5]=fb.y; f[6]=fb.z; f[7]=fb.w;
            f[8]=fc2.x; f[9]=fc2.y;
            #pragma unroll
            for (int k = 0; k < 3; ++k) {
                const float* wrow = &Ws[c * 3 + k][o0];
                float4 wa = *(const float4*)&wrow[0];
                float4 wb = *(const float4*)&wrow[4];
                float w[8] = {wa.x, wa.y, wa.z, wa.w, wb.x, wb.y, wb.z, wb.w};
                #pragma unroll
                for (int oi = 0; oi < 8; ++oi)
                    #pragma unroll
                    for (int li = 0; li < 8; ++li)
                        acc[oi][li] = fmaf(w[oi], f[li + k], acc[oi][li]);
            }
        }
    }
    const int mflag = mflag_p[0];
    const int lbase = l0 + ll;
    float mv[8];
    #pragma unroll
    for (int li = 0; li < 8; ++li) {
        int idx = b * L_ + lbase + li;
        if (mflag == 1)      mv[li] = mask[idx] ? 1.f : 0.f;
        else if (mflag == 0) mv[li] = ((const int*)mask)[idx] ? 1.f : 0.f;
        else                 mv[li] = ((const int*)mask)[2 * idx] ? 1.f : 0.f;
    }
    #pragma unroll
    for (int oi = 0; oi < 8; ++oi) {
        float bo = bias[o0 + oi];
        float* dst = out + ((size_t)b * O_ + o0 + oi) * L_ + lbase;
        #pragma unroll
        for (int li = 0; li < 8; ++li) dst[li] = (acc[oi][li] + bo) * mv[li];
    }
}

extern "C" void kernel_launch(void* const* d_in, const int* in_sizes, int n_in,
                              void* d_out, int out_size, void* d_ws, size_t ws_size,
                              hipStream_t stream) {
    const float*         inputs = (const float*)d_in[0];
    const int*           conn   = (const int*)d_in[1];
    const unsigned char* mask   = (const unsigned char*)d_in[2];
    const float*         W      = (const float*)d_in[3];
    const float*         bias   = (const float*)d_in[4];
    float*               out    = (float*)d_out;

    const size_t g_bytes  = G_ELEMS * sizeof(_Float16);
    const size_t wt_bytes = WT_ELEMS * sizeof(_Float16);
    const size_t need     = g_bytes + wt_bytes + 64;

    if (ws_size < need) {
        int* mflag = (int*)d_ws;
        detect_fused<<<1, 1024, 0, stream>>>((const uint4*)mask, mflag);
        dim3 grid(L_ / 128, B_);
        cc_fallback_kernel<<<grid, 256, 0, stream>>>(inputs, conn, mask, W, bias, out, mflag);
        return;
    }

    _Float16* G     = (_Float16*)d_ws;
    _Float16* Wt    = (_Float16*)((char*)d_ws + g_bytes);
    int*      mflag = (int*)((char*)d_ws + g_bytes + wt_bytes);

    detect_fused<<<1, 1024, 0, stream>>>((const uint4*)mask, mflag);
    prep_kernel<<<2048 + 432, 256, 0, stream>>>(inputs, W, G, Wt);
    k1_gather_penc<<<1024, 256, 0, stream>>>(conn, G);
    k2_gemm<<<256, 512, 0, stream>>>(G, Wt, mask, bias, out, mflag);
}

// Round 10
// 46.909 us; speedup vs baseline: 1.4987x; 1.4987x over previous
//
#include <hip/hip_runtime.h>
#include <math.h>

#define B_    8
#define C_    128
#define L_    8192
#define O_    128
#define POS_  10
#define CHIN  798
#define CH_   266          // 128 direct + 128 gathered + 10 penc
#define CPAD  288          // Wt col stride (9 chunks * 32)
#define GSTR  128          // G row stride (direct channels only)
#define NCH   9
#define TL2   256
#define G_ELEMS  ((size_t)B_ * L_ * GSTR)   // f16: 16.78 MB
#define WT_ELEMS ((size_t)3 * O_ * CPAD)    // f16: 221 KB

typedef _Float16 half8 __attribute__((ext_vector_type(8)));
typedef short short8 __attribute__((ext_vector_type(8)));
typedef float f32x4  __attribute__((ext_vector_type(4)));

// ---------------------------------------------------------------------------
// mask dtype detect core: 256 threads scan 64 KB; mflag 1=byte,0=i32,2=i64
// ---------------------------------------------------------------------------
__device__ __forceinline__ void detect_core(const uint4* __restrict__ m,
                                            int* __restrict__ mflag, int tid) {
    __shared__ int s[2];
    if (tid < 2) s[tid] = 0;
    __syncthreads();
    unsigned sub = 0, mid = 0;
    #pragma unroll
    for (int k = 0; k < 16; ++k) {
        uint4 w = m[tid + k * 256];              // 4096 * 16B = 64 KB
        sub |= (w.x | w.y | w.z | w.w) & 0xFFFFFF00u;
        mid |= (w.y | w.w) & 0x000000FFu;
    }
    unsigned long long bs = __ballot(sub != 0);
    unsigned long long bm = __ballot(mid != 0);
    if ((tid & 63) == 0) {
        if (bs) atomicOr(&s[0], 1);
        if (bm) atomicOr(&s[1], 1);
    }
    __syncthreads();
    if (tid == 0) mflag[0] = s[0] ? 1 : (s[1] ? 0 : 2);
}

__global__ void detect_kernel(const uint4* __restrict__ m, int* __restrict__ mflag) {
    detect_core(m, mflag, threadIdx.x);
}

// ---------------------------------------------------------------------------
// prep: blocks [0,2048): transpose inputs[b,c,l] f32 -> G[b,l,c] f16 (c<128)
//       blocks [2048,2480): Wt[t][o][c] = (f16) W[o][3c+t] (c<266 else 0)
//       block 2480: mask dtype detect
// ---------------------------------------------------------------------------
__global__ __launch_bounds__(256, 4)
void prep_kernel(const float* __restrict__ inputs, const float* __restrict__ W,
                 const uint4* __restrict__ maskv,
                 _Float16* __restrict__ G, _Float16* __restrict__ Wt,
                 int* __restrict__ mflag) {
    __shared__ float tile[64][65];
    const int bid = blockIdx.x;
    const int tid = threadIdx.x;

    if (bid == 2480) { detect_core(maskv, mflag, tid); return; }

    if (bid >= 2048) {   // Wt prep: 432 blocks * 256 = 110,592 elems exact
        int idx = (bid - 2048) * 256 + tid;
        int c   = idx % CPAD;
        int rem = idx / CPAD;
        int o   = rem & 127;
        int t   = rem >> 7;
        Wt[idx] = (c < CH_) ? (_Float16)W[o * CHIN + 3 * c + t] : (_Float16)0.f;
        return;
    }

    const int b  = bid & 7;          // b -> XCD affinity
    const int r  = bid >> 3;
    const int c0 = (r & 1) * 64;
    const int l0 = (r >> 1) * 64;
    const int ty = tid >> 6, tx = tid & 63;

    #pragma unroll
    for (int it = 0; it < 16; ++it) {
        int cl = it * 4 + ty;
        tile[cl][tx] = inputs[((size_t)(b * C_ + c0 + cl)) * L_ + l0 + tx];
    }
    __syncthreads();
    const int cp = (tid & 31) * 2;
    const int lr = tid >> 5;          // 0..7
    #pragma unroll
    for (int it = 0; it < 8; ++it) {
        int ll = it * 8 + lr;
        _Float16 pair[2] = {(_Float16)tile[cp][ll], (_Float16)tile[cp + 1][ll]};
        *(unsigned*)&G[((size_t)(b * L_ + l0 + ll)) * GSTR + c0 + cp] = *(unsigned*)pair;
    }
}

// ---------------------------------------------------------------------------
// K2: f16 MFMA GEMM with in-staging gather + penc.
// grid 256 flat (b = bid&7 -> XCD). 512 thr = 8 waves (2o x 4l), wave 64o x 64l.
// A (Wt) staged in LDS per chunk; B built in LDS per chunk:
//   ch 0-3: direct G rows; ch 4-7: G[conn_s[j]] rows; ch 8: inline sinf penc.
// All global loads for chunk ch+1 issued BEFORE compute of chunk ch (T14).
// ---------------------------------------------------------------------------
__global__ __launch_bounds__(512, 1)
void k2_gemm(const _Float16* __restrict__ G, const _Float16* __restrict__ Wt,
             const int* __restrict__ conn,
             const unsigned char* __restrict__ mask,
             const float* __restrict__ bias,
             float* __restrict__ out,
             const int* __restrict__ mflag_p) {
    __shared__ _Float16 As[3][128][40];   // 30.7 KB [tap][o][c]
    __shared__ _Float16 Bs[260][40];      // 20.8 KB rows l0-1 .. l0+256
    __shared__ int conn_s[260];

    const int bid = blockIdx.x;
    const int b   = bid & 7;
    const int l0  = (bid >> 3) * TL2;
    const int tid  = threadIdx.x;
    const int wave = tid >> 6;
    const int lane = tid & 63;
    const int wo = wave & 1;
    const int wl = wave >> 1;
    const int g  = lane >> 4;
    const int ln = lane & 15;

    const _Float16* gb = G + (size_t)b * L_ * GSTR;

    // stage conn halo (visible after first __syncthreads; first gather use is ch4)
    for (int j = tid; j < TL2 + 2; j += 512) {
        int l_ = l0 - 1 + j;
        conn_s[j] = ((unsigned)l_ < (unsigned)L_) ? conn[b * L_ + l_] : 0;
    }

    // ---- staging helpers (q-index mappings) ----
    // A: q in [0,1536): cb=q&3, o=(q>>2)&127, tp=q>>9 ; thread q's: tid, +512, +1024
    // B: q in [0,1032): cb=q&3, j=q>>2          ; thread q's: tid, +512, (+1024 tid<8)
    auto aload = [&](int ch, int q) -> short8 {
        int cb = q & 3, o = (q >> 2) & 127, tp = q >> 9;
        return *(const short8*)&Wt[((size_t)(tp * O_ + o)) * CPAD + ch * 32 + cb * 8];
    };
    auto bload = [&](int ch, int q) -> short8 {
        int cb = q & 3, j = q >> 2;
        int l_ = l0 - 1 + j;
        short8 v = (short8)0;
        if ((unsigned)l_ < (unsigned)L_) {
            if (ch < 4) {
                v = *(const short8*)&gb[(size_t)l_ * GSTR + ch * 32 + cb * 8];
            } else if (ch < 8) {
                int cj = conn_s[j];
                v = *(const short8*)&gb[(size_t)cj * GSTR + (ch - 4) * 32 + cb * 8];
            } else if (cb < 2) {
                float d = (float)(l_ - conn_s[j]);
                _Float16 h[8];
                #pragma unroll
                for (int e = 0; e < 8; ++e) {
                    int p = cb * 8 + e;
                    h[e] = (p < POS_) ? (_Float16)sinf(((float)(1 << p)) * d / 1000.0f)
                                      : (_Float16)0.f;
                }
                v = *(short8*)h;
            }
        }
        return v;
    };
    auto awrite = [&](short8 s, int q) {
        int cb = q & 3, o = (q >> 2) & 127, tp = q >> 9;
        *(short8*)&As[tp][o][cb * 8] = s;
    };
    auto bwrite = [&](short8 s, int q) {
        int cb = q & 3, j = q >> 2;
        *(short8*)&Bs[j][cb * 8] = s;
    };

    f32x4 acc[4][4];
    #pragma unroll
    for (int m = 0; m < 4; ++m)
        #pragma unroll
        for (int n = 0; n < 4; ++n) acc[m][n] = (f32x4)0.f;

    // prologue: stage chunk 0 (direct rows, no conn dependency)
    {
        short8 a0 = aload(0, tid), a1 = aload(0, tid + 512), a2 = aload(0, tid + 1024);
        short8 s0 = bload(0, tid), s1 = bload(0, tid + 512);
        short8 s2; if (tid < 8) s2 = bload(0, 1024 + tid);
        awrite(a0, tid); awrite(a1, tid + 512); awrite(a2, tid + 1024);
        bwrite(s0, tid); bwrite(s1, tid + 512);
        if (tid < 8) bwrite(s2, 1024 + tid);
    }
    __syncthreads();

    for (int ch = 0; ch < NCH; ++ch) {
        const bool more = (ch + 1 < NCH);

        // issue next-chunk loads early (global latency hides under compute)
        short8 a0, a1, a2, s0, s1, s2;
        if (more) {
            a0 = aload(ch + 1, tid); a1 = aload(ch + 1, tid + 512); a2 = aload(ch + 1, tid + 1024);
            s0 = bload(ch + 1, tid); s1 = bload(ch + 1, tid + 512);
            if (tid < 8) s2 = bload(ch + 1, 1024 + tid);
        }

        // compute from LDS: 3 taps x (4m x 4n)
        #pragma unroll
        for (int t = 0; t < 3; ++t) {
            half8 bf[4];
            #pragma unroll
            for (int n = 0; n < 4; ++n)
                bf[n] = *(const half8*)&Bs[wl * 64 + n * 16 + ln + t][8 * g];
            #pragma unroll
            for (int m = 0; m < 4; ++m) {
                half8 af = *(const half8*)&As[t][wo * 64 + m * 16 + ln][8 * g];
                #pragma unroll
                for (int n = 0; n < 4; ++n)
                    acc[m][n] = __builtin_amdgcn_mfma_f32_16x16x32_f16(af, bf[n], acc[m][n], 0, 0, 0);
            }
        }

        if (more) {
            __syncthreads();   // all waves done reading current LDS
            awrite(a0, tid); awrite(a1, tid + 512); awrite(a2, tid + 1024);
            bwrite(s0, tid); bwrite(s1, tid + 512);
            if (tid < 8) bwrite(s2, 1024 + tid);
            __syncthreads();   // new tiles visible
        }
    }

    // epilogue: D col = lane&15 (l), row = g*4+r (o) within frag
    const int mflag = mflag_p[0];
    float mv[4];
    #pragma unroll
    for (int n = 0; n < 4; ++n) {
        int l = l0 + wl * 64 + n * 16 + ln;
        int idx = b * L_ + l;
        if (mflag == 1)      mv[n] = mask[idx] ? 1.f : 0.f;
        else if (mflag == 0) mv[n] = ((const int*)mask)[idx] ? 1.f : 0.f;
        else                 mv[n] = ((const int*)mask)[2 * idx] ? 1.f : 0.f;
    }
    #pragma unroll
    for (int m = 0; m < 4; ++m) {
        #pragma unroll
        for (int r = 0; r < 4; ++r) {
            int o = wo * 64 + m * 16 + g * 4 + r;
            float bo = bias[o];
            #pragma unroll
            for (int n = 0; n < 4; ++n) {
                int l = l0 + wl * 64 + n * 16 + ln;
                out[((size_t)(b * O_ + o)) * L_ + l] = (acc[m][n][r] + bo) * mv[n];
            }
        }
    }
}

// ---------------------------------------------------------------------------
// Fallback (fp32 vector path) if workspace too small
// ---------------------------------------------------------------------------
__global__ __launch_bounds__(256, 2)
void cc_fallback_kernel(const float* __restrict__ inputs,
                        const int* __restrict__ conn,
                        const unsigned char* __restrict__ mask,
                        const float* __restrict__ W,
                        const float* __restrict__ bias,
                        float* __restrict__ out,
                        const int* __restrict__ mflag_p) {
    __shared__ int   conn_s[130];
    __shared__ float feat_s[16][132];
    __shared__ float Ws[48][136];

    const int b   = blockIdx.y;
    const int l0  = blockIdx.x * 128;
    const int tid = threadIdx.x;
    const int ot  = tid >> 4;
    const int lt  = tid & 15;
    const int o0  = ot * 8;
    const int ll  = lt * 8;

    for (int j = tid; j < 130; j += 256) {
        int lg = l0 - 1 + j;
        conn_s[j] = ((unsigned)lg < (unsigned)L_) ? conn[b * L_ + lg] : -1;
    }
    float acc[8][8];
    #pragma unroll
    for (int i = 0; i < 8; ++i)
        #pragma unroll
        for (int j = 0; j < 8; ++j) acc[i][j] = 0.f;

    const int tc = ot, tj = lt;
    for (int chunk = 0; chunk < 17; ++chunk) {
        const int CN  = (chunk < 16) ? 16 : POS_;
        const int cg0 = chunk * 16;
        const int col0 = 3 * cg0;
        __syncthreads();
        {
            const int nw = O_ * CN * 3;
            for (int idx = tid; idx < nw; idx += 256) {
                int o = idx & 127, kk = idx >> 7;
                Ws[kk][o] = W[o * CHIN + col0 + kk];
            }
        }
        if (chunk < 8) {
            const float* src = inputs + ((size_t)b * C_ + (cg0 + tc)) * L_;
            for (int j = tj; j < 130; j += 16) {
                int lg = l0 - 1 + j;
                feat_s[tc][j] = ((unsigned)lg < (unsigned)L_) ? src[lg] : 0.f;
            }
        } else if (chunk < 16) {
            const float* src = inputs + ((size_t)b * C_ + (cg0 - 128 + tc)) * L_;
            for (int j = tj; j < 130; j += 16) {
                int cj = conn_s[j];
                feat_s[tc][j] = (cj >= 0) ? src[cj] : 0.f;
            }
        } else if (tc < POS_) {
            const float sc = (float)(1 << tc);
            for (int j = tj; j < 130; j += 16) {
                int cj = conn_s[j];
                int lg = l0 - 1 + j;
                float v = 0.f;
                if (cj >= 0) v = sinf((sc * (float)(lg - cj)) / 1000.0f);
                feat_s[tc][j] = v;
            }
        }
        __syncthreads();
        for (int c = 0; c < CN; ++c) {
            float f[10];
            float4 fa = *(const float4*)&feat_s[c][ll];
            float4 fb = *(const float4*)&feat_s[c][ll + 4];
            float2 fc2 = *(const float2*)&feat_s[c][ll + 8];
            f[0]=fa.x; f[1]=fa.y; f[2]=fa.z; f[3]=fa.w;
            f[4]=fb.x; f[5]=fb.y; f[6]=fb.z; f[7]=fb.w;
            f[8]=fc2.x; f[9]=fc2.y;
            #pragma unroll
            for (int k = 0; k < 3; ++k) {
                const float* wrow = &Ws[c * 3 + k][o0];
                float4 wa = *(const float4*)&wrow[0];
                float4 wb = *(const float4*)&wrow[4];
                float w[8] = {wa.x, wa.y, wa.z, wa.w, wb.x, wb.y, wb.z, wb.w};
                #pragma unroll
                for (int oi = 0; oi < 8; ++oi)
                    #pragma unroll
                    for (int li = 0; li < 8; ++li)
                        acc[oi][li] = fmaf(w[oi], f[li + k], acc[oi][li]);
            }
        }
    }
    const int mflag = mflag_p[0];
    const int lbase = l0 + ll;
    float mv[8];
    #pragma unroll
    for (int li = 0; li < 8; ++li) {
        int idx = b * L_ + lbase + li;
        if (mflag == 1)      mv[li] = mask[idx] ? 1.f : 0.f;
        else if (mflag == 0) mv[li] = ((const int*)mask)[idx] ? 1.f : 0.f;
        else                 mv[li] = ((const int*)mask)[2 * idx] ? 1.f : 0.f;
    }
    #pragma unroll
    for (int oi = 0; oi < 8; ++oi) {
        float bo = bias[o0 + oi];
        float* dst = out + ((size_t)b * O_ + o0 + oi) * L_ + lbase;
        #pragma unroll
        for (int li = 0; li < 8; ++li) dst[li] = (acc[oi][li] + bo) * mv[li];
    }
}

extern "C" void kernel_launch(void* const* d_in, const int* in_sizes, int n_in,
                              void* d_out, int out_size, void* d_ws, size_t ws_size,
                              hipStream_t stream) {
    const float*         inputs = (const float*)d_in[0];
    const int*           conn   = (const int*)d_in[1];
    const unsigned char* mask   = (const unsigned char*)d_in[2];
    const float*         W      = (const float*)d_in[3];
    const float*         bias   = (const float*)d_in[4];
    float*               out    = (float*)d_out;

    const size_t g_bytes  = G_ELEMS * sizeof(_Float16);    // 16.78 MB
    const size_t wt_bytes = WT_ELEMS * sizeof(_Float16);   // 221 KB
    const size_t need     = g_bytes + wt_bytes + 64;

    if (ws_size < need) {
        int* mflag = (int*)d_ws;
        detect_kernel<<<1, 256, 0, stream>>>((const uint4*)mask, mflag);
        dim3 grid(L_ / 128, B_);
        cc_fallback_kernel<<<grid, 256, 0, stream>>>(inputs, conn, mask, W, bias, out, mflag);
        return;
    }

    _Float16* G     = (_Float16*)d_ws;
    _Float16* Wt    = (_Float16*)((char*)d_ws + g_bytes);
    int*      mflag = (int*)((char*)d_ws + g_bytes + wt_bytes);

    prep_kernel<<<2481, 256, 0, stream>>>(inputs, W, (const uint4*)mask, G, Wt, mflag);
    k2_gemm<<<256, 512, 0, stream>>>(G, Wt, conn, mask, bias, out, mflag);
}